// Round 7
// baseline (167.374 us; speedup 1.0000x reference)
//
#include <hip/hip_runtime.h>

typedef float v2f __attribute__((ext_vector_type(2)));

constexpr int IN_D = 18, W_HID = 10, N_HID = 19;
constexpr float SLOPE = 0.1f;

// Padded weight image in d_ws (floats):
//   [0    .. 2280) hidden: l*120 + j*12 + k   (k=0..9 weights, k=10 bias, k=11 pad)
//   [2280 .. 2480) W0: r*20 + c               (c=0..17 weights, c=18 bias, c=19 pad)
//   [2480 .. 2492) Wf: [w0..w9, bf, pad]
constexpr int WS_H = 0, WS_L0 = 2280, WS_F = 2480;

__global__ void repack_weights(const float* __restrict__ W0, const float* __restrict__ b0,
                               const float* __restrict__ Ws, const float* __restrict__ bs,
                               const float* __restrict__ Wf, const float* __restrict__ bf,
                               float* __restrict__ wsf) {
    const int tid = threadIdx.x;
    for (int idx = tid; idx < 1900; idx += 256) {
        int l = idx / 100, rem = idx % 100, r = rem / 10, c = rem % 10;
        wsf[WS_H + l * 120 + r * 12 + c] = Ws[idx];
    }
    for (int idx = tid; idx < 190; idx += 256) {
        int l = idx / 10, r = idx % 10;
        wsf[WS_H + l * 120 + r * 12 + 10] = bs[idx];
    }
    for (int idx = tid; idx < 180; idx += 256) {
        int r = idx / 18, c = idx % 18;
        wsf[WS_L0 + r * 20 + c] = W0[idx];
    }
    if (tid < 10) wsf[WS_L0 + tid * 20 + 18] = b0[tid];
    if (tid < 10) wsf[WS_F + tid] = Wf[tid];
    if (tid == 0) wsf[WS_F + 10] = bf[0];
}

__device__ __forceinline__ v2f splat(float s) { v2f v; v[0] = s; v[1] = s; return v; }

__device__ __forceinline__ v2f lrelu2(v2f x) {
    return __builtin_elementwise_max(x, x * splat(SLOPE));
}

// One 10->10 layer; rows of 12 floats [w0..w9, bias, pad] read as 3x global_load_dwordx4 (L1 broadcast).
__device__ __forceinline__ void layer10_vec(const v2f* __restrict__ in, v2f* __restrict__ outv,
                                            const float* __restrict__ Wp) {
    #pragma unroll
    for (int j = 0; j < W_HID; ++j) {
        const float4* row = reinterpret_cast<const float4*>(Wp + j * 12);
        float4 wa = row[0], wb = row[1], wc = row[2];
        v2f acc = splat(wc.z);                          // bias
        acc = __builtin_elementwise_fma(in[0], splat(wa.x), acc);
        acc = __builtin_elementwise_fma(in[1], splat(wa.y), acc);
        acc = __builtin_elementwise_fma(in[2], splat(wa.z), acc);
        acc = __builtin_elementwise_fma(in[3], splat(wa.w), acc);
        acc = __builtin_elementwise_fma(in[4], splat(wb.x), acc);
        acc = __builtin_elementwise_fma(in[5], splat(wb.y), acc);
        acc = __builtin_elementwise_fma(in[6], splat(wb.z), acc);
        acc = __builtin_elementwise_fma(in[7], splat(wb.w), acc);
        acc = __builtin_elementwise_fma(in[8], splat(wc.x), acc);
        acc = __builtin_elementwise_fma(in[9], splat(wc.y), acc);
        outv[j] = lrelu2(acc);
    }
}

// 2 samples/thread, rolled hidden loop, weights via uniform-address VECTOR loads (L1 broadcast).
__global__ __launch_bounds__(256, 5) void critic_pk2_l1(
    const float* __restrict__ state, const float* __restrict__ action,
    const float* __restrict__ wsf_in,
    float* __restrict__ out, int B)
{
    // Taint the weight base with a VGPR so the compiler cannot prove uniformity
    // and must emit global_load (vector path, vmcnt-pipelinable) instead of s_load.
    int zero = 0;
    asm volatile("" : "+v"(zero));
    const float* wsf = wsf_in + zero;

    const int t = blockIdx.x * blockDim.x + threadIdx.x;
    if (t * 2 >= B) return;

    // ---- 2 state rows (96 B, 16B-aligned) ----
    float Sf[24];
    {
        const float4* s4 = reinterpret_cast<const float4*>(state) + (size_t)t * 6;
        #pragma unroll
        for (int r = 0; r < 6; ++r) {
            float4 v = s4[r];
            Sf[4*r] = v.x; Sf[4*r+1] = v.y; Sf[4*r+2] = v.z; Sf[4*r+3] = v.w;
        }
    }
    // ---- 2 action rows (48 B, 16B-aligned) ----
    float Af[12];
    {
        const float4* a4 = reinterpret_cast<const float4*>(action) + (size_t)t * 3;
        #pragma unroll
        for (int r = 0; r < 3; ++r) {
            float4 v = a4[r];
            Af[4*r] = v.x; Af[4*r+1] = v.y; Af[4*r+2] = v.z; Af[4*r+3] = v.w;
        }
    }

    v2f x[IN_D];
    #pragma unroll
    for (int k = 0; k < 12; ++k) { v2f v; v[0] = Sf[k]; v[1] = Sf[12 + k]; x[k] = v; }
    #pragma unroll
    for (int k = 0; k < 6; ++k)  { v2f v; v[0] = Af[k]; v[1] = Af[6 + k];  x[12 + k] = v; }

    // ---- layer 0: 18 -> 10, rows of 20 floats [w0..w17, b, pad] ----
    v2f h[W_HID], g[W_HID];
    #pragma unroll
    for (int j = 0; j < W_HID; ++j) {
        const float4* row = reinterpret_cast<const float4*>(wsf + WS_L0 + j * 20);
        float4 wa = row[0], wb = row[1], wc = row[2], wd = row[3], we = row[4];
        v2f acc = splat(we.z);    // b0[j]
        acc = __builtin_elementwise_fma(x[0],  splat(wa.x), acc);
        acc = __builtin_elementwise_fma(x[1],  splat(wa.y), acc);
        acc = __builtin_elementwise_fma(x[2],  splat(wa.z), acc);
        acc = __builtin_elementwise_fma(x[3],  splat(wa.w), acc);
        acc = __builtin_elementwise_fma(x[4],  splat(wb.x), acc);
        acc = __builtin_elementwise_fma(x[5],  splat(wb.y), acc);
        acc = __builtin_elementwise_fma(x[6],  splat(wb.z), acc);
        acc = __builtin_elementwise_fma(x[7],  splat(wb.w), acc);
        acc = __builtin_elementwise_fma(x[8],  splat(wc.x), acc);
        acc = __builtin_elementwise_fma(x[9],  splat(wc.y), acc);
        acc = __builtin_elementwise_fma(x[10], splat(wc.z), acc);
        acc = __builtin_elementwise_fma(x[11], splat(wc.w), acc);
        acc = __builtin_elementwise_fma(x[12], splat(wd.x), acc);
        acc = __builtin_elementwise_fma(x[13], splat(wd.y), acc);
        acc = __builtin_elementwise_fma(x[14], splat(wd.z), acc);
        acc = __builtin_elementwise_fma(x[15], splat(wd.w), acc);
        acc = __builtin_elementwise_fma(x[16], splat(we.x), acc);
        acc = __builtin_elementwise_fma(x[17], splat(we.y), acc);
        h[j] = lrelu2(acc);
    }

    // ---- 19 hidden layers: rolled, 2 per iteration (ping-pong h->g->h) ----
    const float* lb = wsf + WS_H;
    #pragma unroll 1
    for (int it = 0; it < (N_HID - 1) / 2; ++it) {
        layer10_vec(h, g, lb);
        layer10_vec(g, h, lb + 120);
        lb += 240;
    }
    layer10_vec(h, g, lb);   // layer 18

    // ---- final layer: 10 -> 1 ----
    {
        const float4* row = reinterpret_cast<const float4*>(wsf + WS_F);
        float4 fa = row[0], fb = row[1], fc = row[2];
        v2f acc = splat(fc.z);   // bf
        acc = __builtin_elementwise_fma(g[0], splat(fa.x), acc);
        acc = __builtin_elementwise_fma(g[1], splat(fa.y), acc);
        acc = __builtin_elementwise_fma(g[2], splat(fa.z), acc);
        acc = __builtin_elementwise_fma(g[3], splat(fa.w), acc);
        acc = __builtin_elementwise_fma(g[4], splat(fb.x), acc);
        acc = __builtin_elementwise_fma(g[5], splat(fb.y), acc);
        acc = __builtin_elementwise_fma(g[6], splat(fb.z), acc);
        acc = __builtin_elementwise_fma(g[7], splat(fb.w), acc);
        acc = __builtin_elementwise_fma(g[8], splat(fc.x), acc);
        acc = __builtin_elementwise_fma(g[9], splat(fc.y), acc);
        acc = lrelu2(acc);
        float2 o; o.x = acc[0]; o.y = acc[1];
        reinterpret_cast<float2*>(out)[t] = o;
    }
}

extern "C" void kernel_launch(void* const* d_in, const int* in_sizes, int n_in,
                              void* d_out, int out_size, void* d_ws, size_t ws_size,
                              hipStream_t stream) {
    const float* state  = (const float*)d_in[0];
    const float* action = (const float*)d_in[1];
    const float* W0     = (const float*)d_in[2];
    const float* b0     = (const float*)d_in[3];
    const float* Ws     = (const float*)d_in[4];
    const float* bs     = (const float*)d_in[5];
    const float* Wf     = (const float*)d_in[6];
    const float* bf     = (const float*)d_in[7];
    float* out = (float*)d_out;
    float* wsf = (float*)d_ws;               // needs 2492 floats (~10 KB)

    repack_weights<<<1, 256, 0, stream>>>(W0, b0, Ws, bs, Wf, bf, wsf);

    const int B = out_size;                  // [1, B] flat; B = 1048576 (even)
    const int nthreads = B / 2;              // 2 samples per thread
    const int block = 256;
    const int grid = (nthreads + block - 1) / block;
    critic_pk2_l1<<<grid, block, 0, stream>>>(state, action, wsf, out, B);
}

// Round 8
// 59.122 us; speedup vs baseline: 2.8310x; 2.8310x over previous
//
#include <hip/hip_runtime.h>

typedef float v2f __attribute__((ext_vector_type(2)));

constexpr int IN_D = 18, W_HID = 10, N_HID = 19;
constexpr float SLOPE = 0.1f;

__device__ __forceinline__ v2f splat(float s) { v2f v; v[0] = s; v[1] = s; return v; }

__device__ __forceinline__ v2f lrelu2(v2f x) {
    // max(x, slope*x) == leaky_relu(x) for 0<slope<1 -> v_pk_mul_f32 + v_pk_max_f32
    return __builtin_elementwise_max(x, x * splat(SLOPE));
}

// One 10->10 layer: in -> out, weights at W (100 floats), bias at bb (10 floats).
__device__ __forceinline__ void layer10(const v2f* __restrict__ in, v2f* __restrict__ outv,
                                        const float* __restrict__ W, const float* __restrict__ bb) {
    #pragma unroll
    for (int j = 0; j < W_HID; ++j) {
        v2f acc = splat(bb[j]);
        #pragma unroll
        for (int k = 0; k < W_HID; ++k)
            acc = __builtin_elementwise_fma(in[k], splat(W[j*W_HID + k]), acc);
        outv[j] = lrelu2(acc);
    }
}

// 2 samples/thread, rolled hidden loop (I$-resident), SGPR weights,
// 128-VGPR budget (4 waves/SIMD) so live state fits without AGPR shuffling.
__global__ __launch_bounds__(256, 4) void critic_pk2r4(
    const float* __restrict__ state, const float* __restrict__ action,
    const float* __restrict__ W0, const float* __restrict__ bias0,
    const float* __restrict__ Ws, const float* __restrict__ bs,
    const float* __restrict__ Wf, const float* __restrict__ bf,
    float* __restrict__ out, int B)
{
    const int t = blockIdx.x * blockDim.x + threadIdx.x;
    if (t * 2 >= B) return;

    // ---- 2 state rows (96 B, 16B-aligned) as 6x float4 ----
    float Sf[24];
    {
        const float4* s4 = reinterpret_cast<const float4*>(state) + (size_t)t * 6;
        #pragma unroll
        for (int r = 0; r < 6; ++r) {
            float4 v = s4[r];
            Sf[4*r] = v.x; Sf[4*r+1] = v.y; Sf[4*r+2] = v.z; Sf[4*r+3] = v.w;
        }
    }
    // ---- 2 action rows (48 B, 16B-aligned) as 3x float4 ----
    float Af[12];
    {
        const float4* a4 = reinterpret_cast<const float4*>(action) + (size_t)t * 3;
        #pragma unroll
        for (int r = 0; r < 3; ++r) {
            float4 v = a4[r];
            Af[4*r] = v.x; Af[4*r+1] = v.y; Af[4*r+2] = v.z; Af[4*r+3] = v.w;
        }
    }

    // pack: slot0 = sample 2t, slot1 = sample 2t+1
    v2f x[IN_D];
    #pragma unroll
    for (int k = 0; k < 12; ++k) { v2f v; v[0] = Sf[k]; v[1] = Sf[12 + k]; x[k] = v; }
    #pragma unroll
    for (int k = 0; k < 6; ++k)  { v2f v; v[0] = Af[k]; v[1] = Af[6 + k];  x[12 + k] = v; }

    // ---- layer 0: 18 -> 10 ----
    v2f h[W_HID], g[W_HID];
    #pragma unroll
    for (int j = 0; j < W_HID; ++j) {
        v2f acc = splat(bias0[j]);
        #pragma unroll
        for (int k = 0; k < IN_D; ++k)
            acc = __builtin_elementwise_fma(x[k], splat(W0[j*IN_D + k]), acc);
        h[j] = lrelu2(acc);
    }

    // ---- hidden layers: rolled, 2 per iteration (ping-pong h->g->h) ----
    const float* __restrict__ W  = Ws;
    const float* __restrict__ bb = bs;
    #pragma unroll 1
    for (int it = 0; it < (N_HID - 1) / 2; ++it) {
        layer10(h, g, W,               bb);
        layer10(g, h, W + W_HID*W_HID, bb + W_HID);
        W  += 2 * W_HID * W_HID;
        bb += 2 * W_HID;
    }
    layer10(h, g, W, bb);   // hidden layer 18

    // ---- final layer: 10 -> 1 ----
    v2f acc = splat(bf[0]);
    #pragma unroll
    for (int k = 0; k < W_HID; ++k)
        acc = __builtin_elementwise_fma(g[k], splat(Wf[k]), acc);
    acc = lrelu2(acc);

    float2 o; o.x = acc[0]; o.y = acc[1];
    reinterpret_cast<float2*>(out)[t] = o;   // 8B-aligned coalesced store
}

extern "C" void kernel_launch(void* const* d_in, const int* in_sizes, int n_in,
                              void* d_out, int out_size, void* d_ws, size_t ws_size,
                              hipStream_t stream) {
    const float* state  = (const float*)d_in[0];
    const float* action = (const float*)d_in[1];
    const float* W0     = (const float*)d_in[2];
    const float* b0     = (const float*)d_in[3];
    const float* Ws     = (const float*)d_in[4];
    const float* bs     = (const float*)d_in[5];
    const float* Wf     = (const float*)d_in[6];
    const float* bf     = (const float*)d_in[7];
    float* out = (float*)d_out;

    const int B = out_size;                  // [1, B] flat; B = 1048576 (even)
    const int nthreads = B / 2;              // 2 samples per thread
    const int block = 256;
    const int grid = (nthreads + block - 1) / block;
    critic_pk2r4<<<grid, block, 0, stream>>>(state, action, W0, b0, Ws, bs, Wf, bf, out, B);
}